// Round 7
// baseline (546.735 us; speedup 1.0000x reference)
//
#include <hip/hip_runtime.h>
#include <math.h>

#define Bb 4
#define Ss 2048
#define Ee 1024
#define Hh 16
#define Dd 64

static constexpr int Mtot = Bb * Ss;      // 8192
static constexpr size_t NK = (size_t)Ee * Ee;

typedef __bf16 bf16x8 __attribute__((ext_vector_type(8)));
typedef float  f32x16 __attribute__((ext_vector_type(16)));

extern "C" __device__ float __ocml_native_exp2_f32(float);

__device__ __forceinline__ unsigned short rne1(float x) {
  unsigned u = __float_as_uint(x);
  return (unsigned short)((u + 0x7FFFu + ((u >> 16) & 1u)) >> 16);
}
__device__ __forceinline__ short4 rne4(const float4 v) {
  short4 r;
  r.x = (short)rne1(v.x); r.y = (short)rne1(v.y);
  r.z = (short)rne1(v.z); r.w = (short)rne1(v.w);
  return r;
}

// async global->LDS, 16 B per lane; LDS dest is wave-uniform base + lane*16.
__device__ __forceinline__ void gload16(const unsigned short* g, unsigned short* l) {
  __builtin_amdgcn_global_load_lds((const __attribute__((address_space(1))) void*)g,
                                   (__attribute__((address_space(3))) void*)l,
                                   16, 0, 0);
}

// ---------------------------------------------------------------------------
// prep: RNE-bf16 cast of x and all 4 weights in ONE dispatch.
// Wq/Wk/Wv land concatenated as wqkv[3072][1024]; Wo separate.
// ---------------------------------------------------------------------------
__global__ __launch_bounds__(256) void prep(const float* __restrict__ x,
                                            const float* __restrict__ wq,
                                            const float* __restrict__ wk,
                                            const float* __restrict__ wv,
                                            const float* __restrict__ wo,
                                            unsigned short* __restrict__ xb,
                                            unsigned short* __restrict__ wqkv,
                                            unsigned short* __restrict__ wob) {
  const int X4 = (int)((size_t)Mtot * Ee / 4);  // 2097152
  const int W4 = (int)(NK / 4);                 // 262144
  const int i = blockIdx.x * 256 + threadIdx.x;
  const float* src;
  unsigned short* dst;
  int off;
  if (i < X4) {
    src = x; dst = xb; off = i;
  } else {
    const int j = i - X4;
    const int seg = j >> 18;
    off = j & (W4 - 1);
    if (seg == 0)      { src = wq; dst = wqkv; }
    else if (seg == 1) { src = wk; dst = wqkv + NK; }
    else if (seg == 2) { src = wv; dst = wqkv + 2 * NK; }
    else               { src = wo; dst = wob; }
  }
  float4 v = ((const float4*)src)[off];
  ((short4*)dst)[off] = rne4(v);
}

// ---------------------------------------------------------------------------
// bf16 MFMA GEMM core, m97-style: global_load_lds(16B) staging, 2-barrier
// K-loop, BK=64, 128x128 tile, 256 thr = 4 waves, 2x2 subtiles 32x32x16.
// LDS is unpadded [128][64] shorts with XOR chunk swizzle: the 16B chunk c
// of row r lives at physical chunk c^(r&7). Implemented by permuting each
// lane's SOURCE chunk ((l&7)^(l>>3)); LDS dest stays lane-contiguous as
// global_load_lds requires. Frag b128 reads then cover all 32 banks per
// 8-lane group -> conflict-free (verified by hand).
// ---------------------------------------------------------------------------
__device__ __forceinline__ void gemm_core(const unsigned short* __restrict__ A,
                                          const unsigned short* __restrict__ W,
                                          unsigned short* sm, int bm, int bn,
                                          int tid, f32x16 acc[2][2]) {
  unsigned short* sA = sm;          // [128][64]
  unsigned short* sW = sm + 8192;
  const int lane = tid & 63, w = tid >> 6;
  const int wm = (w & 1) << 6, wn = (w >> 1) << 6;
  const int m32 = lane & 31, g = lane >> 5;
  const int r7 = m32 & 7;
  const int lr = lane >> 3;                 // row within 8-row group
  const int lc = ((lane & 7) ^ lr) << 3;    // swizzled source chunk (shorts)

  const unsigned short* As = A + (size_t)(bm + (w << 5) + lr) * Ee + lc;
  const unsigned short* Ws = W + (size_t)(bn + (w << 5) + lr) * Ee + lc;
  unsigned short* dA = sA + (w << 11);      // wave's 32-row LDS region
  unsigned short* dW = sW + (w << 11);

  for (int k0 = 0; k0 < Ee; k0 += 64) {
    __syncthreads(); // prior iteration's frag reads complete
#pragma unroll
    for (int j = 0; j < 4; ++j) {
      gload16(As + (size_t)(j << 3) * Ee + k0, dA + (j << 9));
      gload16(Ws + (size_t)(j << 3) * Ee + k0, dW + (j << 9));
    }
    __syncthreads(); // barrier drains vmcnt: staging complete
#pragma unroll
    for (int kk = 0; kk < 64; kk += 16) {
      const int pc = ((((kk >> 3) + g) ^ r7) << 3); // physical chunk offset
      bf16x8 af[2], wf[2];
#pragma unroll
      for (int s = 0; s < 2; ++s) {
        af[s] = *(const bf16x8*)(sA + (wm + (s << 5) + m32) * 64 + pc);
        wf[s] = *(const bf16x8*)(sW + (wn + (s << 5) + m32) * 64 + pc);
      }
#pragma unroll
      for (int si = 0; si < 2; ++si)
#pragma unroll
        for (int sj = 0; sj < 2; ++sj)
          acc[si][sj] = __builtin_amdgcn_mfma_f32_32x32x16_bf16(af[si], wf[sj], acc[si][sj], 0, 0, 0);
    }
  }
}

// C/D layout: col = lane&31 (+subtile), row = (g<<2)+(reg&3)+((reg>>2)<<3) (+subtile)

// ---------------------------------------------------------------------------
// Fused QKV projection. N=3072 (wqkv concat). blockIdx.y: 0-7 Q, 8-15 K,
// 16-23 V. Q: *(log2e/8), RNE, [b][h][s][d]. K: RNE, [b][h][s][d].
// V: RNE, transposed [b][h][d][s].
// ---------------------------------------------------------------------------
__global__ __launch_bounds__(256) void gemm_qkv(const unsigned short* __restrict__ xb,
                                                const unsigned short* __restrict__ wqkv,
                                                const float* __restrict__ bq,
                                                const float* __restrict__ bk,
                                                const float* __restrict__ bv,
                                                unsigned short* __restrict__ Qb,
                                                unsigned short* __restrict__ Kb,
                                                unsigned short* __restrict__ Vt) {
  __shared__ unsigned short sm[16384];
  f32x16 acc[2][2] = {};
  const int tid = threadIdx.x;
  const int bm = blockIdx.x << 7, bn = blockIdx.y << 7;
  gemm_core(xb, wqkv, sm, bm, bn, tid, acc);

  const int lane = tid & 63, w = tid >> 6;
  const int wm = (w & 1) << 6, wn = (w >> 1) << 6;
  const int m32 = lane & 31, g = lane >> 5;
  const int proj = blockIdx.y >> 3;                 // 0=Q 1=K 2=V
  const int cb   = (blockIdx.y & 7) << 7;           // col base within 1024
  const float* bp = proj == 0 ? bq : (proj == 1 ? bk : bv);
  const float SC = 0.18033688011112042f;            // log2(e)/8

  if (proj == 2) { // V transposed
    const int bmS = bm & (Ss - 1);
    const int b = bm >> 11;
#pragma unroll
    for (int si = 0; si < 2; ++si)
#pragma unroll
      for (int sj = 0; sj < 2; ++sj) {
        const int col = cb + wn + (sj << 5) + m32;
        const int hh = col >> 6, dd = col & 63;
        const float bvv = bp[col];
        unsigned short* vrow = Vt + ((size_t)((b * Hh + hh) * Dd + dd)) * Ss;
#pragma unroll
        for (int rq = 0; rq < 4; ++rq) {
          const int s0 = bmS + wm + (si << 5) + (g << 2) + (rq << 3);
          float4 v;
          v.x = acc[si][sj][rq * 4 + 0] + bvv;
          v.y = acc[si][sj][rq * 4 + 1] + bvv;
          v.z = acc[si][sj][rq * 4 + 2] + bvv;
          v.w = acc[si][sj][rq * 4 + 3] + bvv;
          *(short4*)(vrow + s0) = rne4(v);
        }
      }
  } else {
    unsigned short* dst = proj == 0 ? Qb : Kb;
    const float sc = proj == 0 ? SC : 1.0f;
#pragma unroll
    for (int si = 0; si < 2; ++si)
#pragma unroll
      for (int sj = 0; sj < 2; ++sj) {
        const int col = cb + wn + (sj << 5) + m32;
        const int hh = col >> 6, dd = col & 63;
        const float bvv = bp[col];
#pragma unroll
        for (int reg = 0; reg < 16; ++reg) {
          const int row = bm + wm + (si << 5) + (g << 2) + (reg & 3) + ((reg >> 2) << 3);
          const int b = row >> 11, s = row & (Ss - 1);
          dst[((size_t)((b * Hh + hh) * Ss + s)) * Dd + dd] =
              rne1((acc[si][sj][reg] + bvv) * sc);
        }
      }
  }
}

// ---------------------------------------------------------------------------
// Output projection: attn-out(bf16) @ Wo^T + bo, fp32 out.
// ---------------------------------------------------------------------------
__global__ __launch_bounds__(256) void gemm_out(const unsigned short* __restrict__ Ab,
                                                const unsigned short* __restrict__ Wb,
                                                const float* __restrict__ bias,
                                                float* __restrict__ C) {
  __shared__ unsigned short sm[16384];
  f32x16 acc[2][2] = {};
  const int tid = threadIdx.x;
  const int bm = blockIdx.x << 7, bn = blockIdx.y << 7;
  gemm_core(Ab, Wb, sm, bm, bn, tid, acc);
  const int lane = tid & 63, w = tid >> 6;
  const int wm = (w & 1) << 6, wn = (w >> 1) << 6;
  const int m32 = lane & 31, g = lane >> 5;
#pragma unroll
  for (int si = 0; si < 2; ++si)
#pragma unroll
    for (int sj = 0; sj < 2; ++sj) {
      const int col = bn + wn + (sj << 5) + m32;
      const float bv = bias[col];
#pragma unroll
      for (int reg = 0; reg < 16; ++reg) {
        const int row = bm + wm + (si << 5) + (g << 2) + (reg & 3) + ((reg >> 2) << 3);
        C[(size_t)row * Ee + col] = acc[si][sj][reg] + bv;
      }
    }
}

// ---------------------------------------------------------------------------
// MFMA flash attention, R7: 128-thread blocks (2 waves, 64 Q rows) -> grid
// 2048 blocks, up to ~8 resident blocks/CU for latency hiding (was 2).
// Same math as R6: no-max exp2 softmax, LDS-staged K/V (stride 72, zero
// conflicts) with register prefetch, perm+shfl P re-layout, RNE-bf16 O.
// ---------------------------------------------------------------------------
__global__ __launch_bounds__(128) void flash_mfma(const unsigned short* __restrict__ Qb,
                                                  const unsigned short* __restrict__ Kb,
                                                  const unsigned short* __restrict__ Vt,
                                                  unsigned short* __restrict__ Ob) {
  __shared__ unsigned short smem[9216]; // Kh[64][72] + Vh[64][72]; reused as Of[64][72]
  unsigned short* Kh = smem;
  unsigned short* Vh = smem + 4608;
  const int tid = threadIdx.x;
  const int lane = tid & 63, w = tid >> 6;   // w in {0,1}
  const int m32 = lane & 31, g = lane >> 5;
  const int qt = blockIdx.x << 6;            // 64 Q rows per block
  const int bh = blockIdx.y;

  const size_t ph = (size_t)bh * Ss * Dd;
  // Q B-frags for this wave's 32 q-columns, cached for the whole loop
  const unsigned short* qp = Qb + ph + (size_t)(qt + (w << 5) + m32) * Dd + (g << 3);
  bf16x8 qf[4];
#pragma unroll
  for (int c = 0; c < 4; ++c) qf[c] = *(const bf16x8*)(qp + (c << 4));

  // staging: thread -> (row sr, 32-short half at sc)
  const int sr = tid >> 1;          // 0..63
  const int sc = (tid & 1) << 5;    // 0 or 32
  const unsigned short* kg = Kb + ph + (size_t)sr * Dd + sc;
  const unsigned short* vg = Vt + (size_t)bh * Dd * Ss + (size_t)sr * Ss + sc;
  const int so = sr * 72 + sc;

  uint4 kv[4], vv[4];
#pragma unroll
  for (int i = 0; i < 4; ++i) {
    kv[i] = *(const uint4*)(kg + (i << 3));
    vv[i] = *(const uint4*)(vg + (i << 3));
  }

  f32x16 acc_o[2] = {}; // O^T: [d, q], col=lane=q
  float l_ = 0.f;

  for (int kt = 0; kt < Ss; kt += 64) {
    __syncthreads(); // prior tile's frag reads complete
#pragma unroll
    for (int i = 0; i < 4; ++i) {
      *(uint4*)(&Kh[so + (i << 3)]) = kv[i];
      *(uint4*)(&Vh[so + (i << 3)]) = vv[i];
    }
    __syncthreads();
    if (kt + 64 < Ss) { // prefetch next tile: latency overlaps compute below
      const unsigned short* kg2 = kg + (size_t)(kt + 64) * Dd;
      const unsigned short* vg2 = vg + (kt + 64);
#pragma unroll
      for (int i = 0; i < 4; ++i) {
        kv[i] = *(const uint4*)(kg2 + (i << 3));
        vv[i] = *(const uint4*)(vg2 + (i << 3));
      }
    }

    // ---- S^T = K.Q^T (exp2 domain), then p = exp2(s) directly (no max)
    float p[2][16];
#pragma unroll
    for (int mt = 0; mt < 2; ++mt) {
      f32x16 a = {};
#pragma unroll
      for (int c = 0; c < 4; ++c) {
        bf16x8 kf = *(const bf16x8*)(&Kh[((mt << 5) + m32) * 72 + (c << 4) + (g << 3)]);
        a = __builtin_amdgcn_mfma_f32_32x32x16_bf16(kf, qf[c], a, 0, 0, 0);
      }
#pragma unroll
      for (int r = 0; r < 16; ++r) p[mt][r] = a[r];
    }
    float rs = 0.f;
#pragma unroll
    for (int mt = 0; mt < 2; ++mt)
#pragma unroll
      for (int r = 0; r < 16; ++r) {
        float e = __ocml_native_exp2_f32(p[mt][r]);
        e = __uint_as_float(__float_as_uint(e) & 0xFFFF0000u); // bf16-truncate
        p[mt][r] = e;
        rs += e; // sum of ROUNDED p: normalization bias cancels
      }
    rs += __shfl_xor(rs, 32); // lanes l, l^32 share col q
    l_ += rs;

    // ---- PV: O^T += V^T . P  (P C-layout -> B-frag: perm-pack then swap)
#pragma unroll
    for (int c = 0; c < 4; ++c) {
      const int mt = c >> 1, b8 = (c & 1) << 3;
      unsigned dw0 = __builtin_amdgcn_perm(__float_as_uint(p[mt][b8 + 1]), __float_as_uint(p[mt][b8 + 0]), 0x07060302u);
      unsigned dw1 = __builtin_amdgcn_perm(__float_as_uint(p[mt][b8 + 3]), __float_as_uint(p[mt][b8 + 2]), 0x07060302u);
      unsigned dw2 = __builtin_amdgcn_perm(__float_as_uint(p[mt][b8 + 5]), __float_as_uint(p[mt][b8 + 4]), 0x07060302u);
      unsigned dw3 = __builtin_amdgcn_perm(__float_as_uint(p[mt][b8 + 7]), __float_as_uint(p[mt][b8 + 6]), 0x07060302u);
      const unsigned tw0 = (unsigned)__shfl_xor((int)dw0, 32);
      const unsigned tw1 = (unsigned)__shfl_xor((int)dw1, 32);
      const unsigned tw2 = (unsigned)__shfl_xor((int)dw2, 32);
      const unsigned tw3 = (unsigned)__shfl_xor((int)dw3, 32);
      union { unsigned u[4]; bf16x8 v; } pf;
      pf.u[0] = g ? tw2 : dw0;
      pf.u[1] = g ? tw3 : dw1;
      pf.u[2] = g ? dw2 : tw0;
      pf.u[3] = g ? dw3 : tw1;
#pragma unroll
      for (int dt = 0; dt < 2; ++dt) {
        bf16x8 vf = *(const bf16x8*)(&Vh[((dt << 5) + m32) * 72 + (c << 4) + (g << 3)]);
        acc_o[dt] = __builtin_amdgcn_mfma_f32_32x32x16_bf16(vf, pf.v, acc_o[dt], 0, 0, 0);
      }
    }
  }

  // ---- epilogue: normalize, RNE-bf16, one LDS transpose pass, uint4 stores
  const float inv = 1.0f / l_;
  const int q = (w << 5) + m32;     // 0..63
  unsigned short* Of = smem;        // [64][72]
  __syncthreads(); // last tile's frag reads complete before overwrite
#pragma unroll
  for (int dt = 0; dt < 2; ++dt)
#pragma unroll
    for (int r = 0; r < 16; ++r) {
      const int d = (dt << 5) + (g << 2) + (r & 3) + ((r >> 2) << 3);
      Of[q * 72 + d] = rne1(acc_o[dt][r] * inv);
    }
  __syncthreads();
  const int orow = tid >> 1, oc = (tid & 1) << 5;
  const int bq = bh >> 4, hh = bh & 15;
  const size_t obase = ((size_t)(bq * Ss + qt + orow)) * Ee + hh * Dd + oc;
#pragma unroll
  for (int i = 0; i < 4; ++i)
    *(uint4*)(Ob + obase + (i << 3)) = *(const uint4*)(&Of[orow * 72 + oc + (i << 3)]);
}

extern "C" void kernel_launch(void* const* d_in, const int* in_sizes, int n_in,
                              void* d_out, int out_size, void* d_ws, size_t ws_size,
                              hipStream_t stream) {
  const float* x  = (const float*)d_in[0];
  const float* Wq = (const float*)d_in[1];
  const float* bq = (const float*)d_in[2];
  const float* Wk = (const float*)d_in[3];
  const float* bk = (const float*)d_in[4];
  const float* Wv = (const float*)d_in[5];
  const float* bv = (const float*)d_in[6];
  const float* Wo = (const float*)d_in[7];
  const float* bo = (const float*)d_in[8];
  float* out = (float*)d_out;

  const size_t nX = (size_t)Mtot * Ee; // 8388608
  unsigned short* xb   = (unsigned short*)d_ws;
  unsigned short* qb   = xb + nX;
  unsigned short* kb   = qb + nX;
  unsigned short* vt   = kb + nX;
  unsigned short* ob   = vt + nX;
  unsigned short* wqkv = ob + nX;        // 3*NK
  unsigned short* wob  = wqkv + 3 * NK;  // NK

  const int total4 = (int)(nX / 4 + NK);
  prep<<<total4 / 256, 256, 0, stream>>>(x, Wq, Wk, Wv, Wo, xb, wqkv, wob);

  gemm_qkv<<<dim3(Mtot / 128, 3 * Ee / 128), 256, 0, stream>>>(xb, wqkv, bq, bk, bv, qb, kb, vt);

  flash_mfma<<<dim3(Ss / 64, Bb * Hh), 128, 0, stream>>>(qb, kb, vt, ob);

  gemm_out<<<dim3(Mtot / 128, Ee / 128), 256, 0, stream>>>(ob, wob, bo, out);
}